// Round 1
// baseline (613.205 us; speedup 1.0000x reference)
//
#include <hip/hip_runtime.h>

#define BB 4
#define VV 256
#define HH 128
#define NROWS (BB*VV)            // 1024
#define NE_CNT (BB*VV*VV)        // 262144
#define EPSV 1e-5f

typedef float4 f4;

__device__ __forceinline__ float sigm(float x) {
    return 1.f / (1.f + __expf(-x));
}

// ---------------------------------------------------------------------------
// K1: Uh/Vh/Ah/Bh = h @ W{U,V,A,B}^T + b   (1024 x 128, K=128)
// grid 256 blocks x 256 thr; each block: 4 rows, thread = (channel n, 2 of 4 W)
// ---------------------------------------------------------------------------
__global__ __launch_bounds__(256) void k_linear4(
    const float* __restrict__ h,
    const float* __restrict__ W0, const float* __restrict__ b0,
    const float* __restrict__ W1, const float* __restrict__ b1,
    const float* __restrict__ W2, const float* __restrict__ b2,
    const float* __restrict__ W3, const float* __restrict__ b3,
    float* __restrict__ out)
{
    __shared__ float hs[4*HH];
    const int tid = threadIdx.x;
    const int r0  = blockIdx.x * 4;
    if (tid < 128) {
        int r = tid >> 5, kq = (tid & 31) << 2;
        *(f4*)&hs[r*HH + kq] = *(const f4*)&h[(r0 + r)*HH + kq];
    }
    __syncthreads();
    const int n  = tid & 127;
    const int s0 = tid >> 7;                       // 0 or 1
    const float* Ws[4] = {W0, W1, W2, W3};
    const float* bs[4] = {b0, b1, b2, b3};
    for (int ss = 0; ss < 2; ++ss) {
        const int sel = s0 + ss*2;
        const float* wrow = Ws[sel] + n*HH;
        float a0=0.f, a1=0.f, a2=0.f, a3=0.f;
        for (int kq = 0; kq < 32; ++kq) {
            f4 w = *(const f4*)&wrow[kq<<2];
            float wq[4] = {w.x, w.y, w.z, w.w};
            #pragma unroll
            for (int q = 0; q < 4; ++q) {
                int k = (kq<<2) + q;
                float wv = wq[q];
                a0 += hs[0*HH + k] * wv;           // same-addr broadcast: free
                a1 += hs[1*HH + k] * wv;
                a2 += hs[2*HH + k] * wv;
                a3 += hs[3*HH + k] * wv;
            }
        }
        float bias = bs[sel][n];
        float* o = out + sel*(NROWS*HH);
        o[(r0+0)*HH + n] = a0 + bias;
        o[(r0+1)*HH + n] = a1 + bias;
        o[(r0+2)*HH + n] = a2 + bias;
        o[(r0+3)*HH + n] = a3 + bias;
    }
}

// ---------------------------------------------------------------------------
// K1b: WCt[k][n] = WC[n][k]  (128x128, LDS-tiled transpose)
// ---------------------------------------------------------------------------
__global__ __launch_bounds__(256) void k_transpose(
    const float* __restrict__ in, float* __restrict__ out)
{
    __shared__ float t[32][33];
    int ti = blockIdx.x >> 2, tj = blockIdx.x & 3;
    int tx = threadIdx.x & 31, ty = threadIdx.x >> 5;   // ty 0..7
    for (int yy = ty; yy < 32; yy += 8)
        t[yy][tx] = in[(ti*32 + yy)*HH + tj*32 + tx];
    __syncthreads();
    for (int yy = ty; yy < 32; yy += 8)
        out[(tj*32 + yy)*HH + ti*32 + tx] = t[tx][yy];
}

// ---------------------------------------------------------------------------
// K2: per (b,i): Ce GEMM (256j x 128n, K=128) fused with e_new build, e_new
// store, sigmoid gating, agg_S, agg_A, and e-batchnorm channel sums.
// 256 thr: tn=tid&15 (8 channels), tj=tid>>4 (4 j's / chunk of 64).
// LDS ~50KB -> 3 blocks/CU. k rotated by tj*8 -> conflict-free es reads.
// ---------------------------------------------------------------------------
__global__ __launch_bounds__(256) void k_edge(
    const float* __restrict__ e, const int* __restrict__ A, const int* __restrict__ S,
    const float* __restrict__ WCt, const float* __restrict__ bC,
    const float* __restrict__ Ahw, const float* __restrict__ Bhw,
    const float* __restrict__ Vhw,
    float* __restrict__ eout, float* __restrict__ aggS, float* __restrict__ aggA,
    float* __restrict__ sums)
{
    __shared__ float wc[64*HH];     // 32KB: wc[kk][n], current k-half
    __shared__ float es[64*64];     // 16KB: es[jl][kk], current (j-chunk, k-half)
    __shared__ float s_aggS[HH], s_aggA[HH], s_sum[HH], s_ssq[HH];

    const int tid = threadIdx.x;
    const int bi  = blockIdx.x;          // b*V + i
    const int b   = bi >> 8;
    if (tid < HH) { s_aggS[tid]=0.f; s_aggA[tid]=0.f; s_sum[tid]=0.f; s_ssq[tid]=0.f; }

    const int tn = tid & 15;
    const int tj = tid >> 4;             // 0..15
    const int n0 = tn << 3;

    float bcv[8], bhv[8];
    #pragma unroll
    for (int q = 0; q < 8; ++q) {
        bcv[q] = bC[n0+q];
        bhv[q] = Bhw[bi*HH + n0 + q];    // Bh[b,i,n]
    }
    const int* Sp = S + bi*VV;
    const int* Ap = A + bi*VV;
    const f4* ef4   = (const f4*)e;
    const f4* wctf4 = (const f4*)WCt;

    for (int jc = 0; jc < 4; ++jc) {
        float acc[4][8];
        #pragma unroll
        for (int jj = 0; jj < 4; ++jj)
            #pragma unroll
            for (int q = 0; q < 8; ++q) acc[jj][q] = 0.f;

        for (int kh = 0; kh < 2; ++kh) {
            __syncthreads();
            #pragma unroll
            for (int m = 0; m < 8; ++m)          // stage WCt half (8192 f)
                ((f4*)wc)[tid + m*256] = wctf4[kh*2048 + tid + m*256];
            #pragma unroll
            for (int m = 0; m < 4; ++m) {        // stage e tile (64j x 64k)
                int item = tid + m*256;
                int j = item >> 4, kq = item & 15;
                ((f4*)es)[item] = ef4[(bi*VV + jc*64 + j)*32 + kh*16 + kq];
            }
            __syncthreads();
            for (int kk = 0; kk < 64; ++kk) {
                int k = (kk + tj*8) & 63;        // rotate: kill bank conflicts
                f4 wa = *(const f4*)&wc[k*HH + n0];
                f4 wb = *(const f4*)&wc[k*HH + n0 + 4];
                #pragma unroll
                for (int jj = 0; jj < 4; ++jj) {
                    float ev = es[(tj*4 + jj)*64 + k];
                    acc[jj][0] += ev*wa.x; acc[jj][1] += ev*wa.y;
                    acc[jj][2] += ev*wa.z; acc[jj][3] += ev*wa.w;
                    acc[jj][4] += ev*wb.x; acc[jj][5] += ev*wb.y;
                    acc[jj][6] += ev*wb.z; acc[jj][7] += ev*wb.w;
                }
            }
        }
        // epilogue for this j-chunk
        float aS[8], aA[8], sm[8], sq[8];
        #pragma unroll
        for (int q = 0; q < 8; ++q) { aS[q]=0.f; aA[q]=0.f; sm[q]=0.f; sq[q]=0.f; }
        #pragma unroll
        for (int jj = 0; jj < 4; ++jj) {
            int j = jc*64 + tj*4 + jj;
            const float* ahp = &Ahw[(b*VV + j)*HH + n0];   // Ah[b,j,n]
            float env[8];
            #pragma unroll
            for (int q = 0; q < 8; ++q)
                env[q] = acc[jj][q] + bcv[q] + bhv[q] + ahp[q];
            size_t eoff = ((size_t)bi*VV + j)*HH + n0;
            *(f4*)&eout[eoff]     = make_float4(env[0],env[1],env[2],env[3]);
            *(f4*)&eout[eoff + 4] = make_float4(env[4],env[5],env[6],env[7]);
            const float* vhp = &Vhw[(b*VV + j)*HH + n0];   // Vh[b,j,n]
            int Sij = Sp[j], Aij = Ap[j];
            #pragma unroll
            for (int q = 0; q < 8; ++q) {
                float v = env[q];
                sm[q] += v;
                sq[q] += v*v;
                float vh = vhp[q];
                if (!Aij) aA[q] += vh;
                if (!Sij) aS[q] += vh * sigm(v);
            }
        }
        #pragma unroll
        for (int q = 0; q < 8; ++q) {
            atomicAdd(&s_sum[n0+q],  sm[q]);
            atomicAdd(&s_ssq[n0+q],  sq[q]);
            atomicAdd(&s_aggS[n0+q], aS[q]);
            atomicAdd(&s_aggA[n0+q], aA[q]);
        }
    }
    __syncthreads();
    if (tid < HH) {
        aggS[bi*HH + tid] = s_aggS[tid];
        aggA[bi*HH + tid] = s_aggA[tid];
        atomicAdd(&sums[tid],      s_sum[tid]);   // e channel sum
        atomicAdd(&sums[HH + tid], s_ssq[tid]);   // e channel sumsq
    }
}

// ---------------------------------------------------------------------------
// K3a: h_new = Uh + aggS + aggA ; accumulate h channel sums
// ---------------------------------------------------------------------------
__global__ __launch_bounds__(256) void k_hnew(
    const float* __restrict__ Uh, const float* __restrict__ aggS,
    const float* __restrict__ aggA, float* __restrict__ h_new,
    float* __restrict__ sums)
{
    __shared__ float ssm[HH], ssq[HH];
    const int tid = threadIdx.x;
    if (tid < 128) { ssm[tid]=0.f; ssq[tid]=0.f; }
    __syncthreads();
    int gid = blockIdx.x*256 + tid;
    f4 u = *(const f4*)&Uh[gid*4];
    f4 s = *(const f4*)&aggS[gid*4];
    f4 a = *(const f4*)&aggA[gid*4];
    float v0=u.x+s.x+a.x, v1=u.y+s.y+a.y, v2=u.z+s.z+a.z, v3=u.w+s.w+a.w;
    *(f4*)&h_new[gid*4] = make_float4(v0,v1,v2,v3);
    int n0 = (gid*4) & 127;
    atomicAdd(&ssm[n0+0], v0); atomicAdd(&ssq[n0+0], v0*v0);
    atomicAdd(&ssm[n0+1], v1); atomicAdd(&ssq[n0+1], v1*v1);
    atomicAdd(&ssm[n0+2], v2); atomicAdd(&ssq[n0+2], v2*v2);
    atomicAdd(&ssm[n0+3], v3); atomicAdd(&ssq[n0+3], v3*v3);
    __syncthreads();
    if (tid < 128) {
        atomicAdd(&sums[256 + tid], ssm[tid]);
        atomicAdd(&sums[384 + tid], ssq[tid]);
    }
}

// ---------------------------------------------------------------------------
// K3b: finalize batchnorm params -> scale/shift per channel
// ---------------------------------------------------------------------------
__global__ void k_stats(const float* __restrict__ sums, float* __restrict__ outs,
                        const float* __restrict__ gamma_e, const float* __restrict__ beta_e,
                        const float* __restrict__ gamma_h, const float* __restrict__ beta_h)
{
    int n = threadIdx.x;   // 128
    float em  = sums[n] * (1.f/(float)NE_CNT);
    float ev  = sums[128+n] * (1.f/(float)NE_CNT) - em*em;
    float esc = rsqrtf(ev + EPSV) * gamma_e[n];
    outs[n]       = esc;
    outs[128 + n] = beta_e[n] - em*esc;
    float hm  = sums[256+n] * (1.f/1024.f);
    float hv  = sums[384+n] * (1.f/1024.f) - hm*hm;
    float hsc = rsqrtf(hv + EPSV) * gamma_h[n];
    outs[256 + n] = hsc;
    outs[384 + n] = beta_h[n] - hm*hsc;
}

// ---------------------------------------------------------------------------
// K4h: h_out = h_in + relu(bn(h_new))
// ---------------------------------------------------------------------------
__global__ __launch_bounds__(256) void k_hout(
    const float* __restrict__ h_in, const float* __restrict__ h_new,
    const float* __restrict__ outs, float* __restrict__ hout)
{
    int gid = blockIdx.x*256 + threadIdx.x;
    int n0 = (gid*4) & 127;
    f4 x  = *(const f4*)&h_new[gid*4];
    f4 hi = *(const f4*)&h_in[gid*4];
    f4 sc = *(const f4*)&outs[256 + n0];
    f4 sh = *(const f4*)&outs[384 + n0];
    f4 y;
    y.x = fmaxf(x.x*sc.x + sh.x, 0.f) + hi.x;
    y.y = fmaxf(x.y*sc.y + sh.y, 0.f) + hi.y;
    y.z = fmaxf(x.z*sc.z + sh.z, 0.f) + hi.z;
    y.w = fmaxf(x.w*sc.w + sh.w, 0.f) + hi.w;
    *(f4*)&hout[gid*4] = y;
}

// ---------------------------------------------------------------------------
// K4e: e_out = e_in + relu(bn(e_new))   (e_new lives in-place in d_out)
// ---------------------------------------------------------------------------
__global__ __launch_bounds__(256) void k_eout(
    const float* __restrict__ e_in, const float* __restrict__ outs,
    float* __restrict__ eio)
{
    size_t gid = (size_t)blockIdx.x*256 + threadIdx.x;
    int n0 = ((int)(gid & 31)) << 2;
    f4 x  = *(const f4*)&eio[gid*4];
    f4 ei = *(const f4*)&e_in[gid*4];
    f4 sc = *(const f4*)&outs[n0];
    f4 sh = *(const f4*)&outs[128 + n0];
    f4 y;
    y.x = fmaxf(x.x*sc.x + sh.x, 0.f) + ei.x;
    y.y = fmaxf(x.y*sc.y + sh.y, 0.f) + ei.y;
    y.z = fmaxf(x.z*sc.z + sh.z, 0.f) + ei.z;
    y.w = fmaxf(x.w*sc.w + sh.w, 0.f) + ei.w;
    *(f4*)&eio[gid*4] = y;
}

// ---------------------------------------------------------------------------
extern "C" void kernel_launch(void* const* d_in, const int* in_sizes, int n_in,
                              void* d_out, int out_size, void* d_ws, size_t ws_size,
                              hipStream_t stream)
{
    (void)in_sizes; (void)n_in; (void)out_size; (void)ws_size;
    const float* h   = (const float*)d_in[0];
    const float* e   = (const float*)d_in[1];
    const int*   A   = (const int*)d_in[2];
    const int*   S   = (const int*)d_in[3];
    const float* WU  = (const float*)d_in[4];   const float* bU = (const float*)d_in[5];
    const float* WV  = (const float*)d_in[6];   const float* bV = (const float*)d_in[7];
    const float* WA_ = (const float*)d_in[8];   const float* bA = (const float*)d_in[9];
    const float* WB_ = (const float*)d_in[10];  const float* bB = (const float*)d_in[11];
    const float* WC_ = (const float*)d_in[12];  const float* bC = (const float*)d_in[13];
    const float* gamma_h = (const float*)d_in[14]; const float* beta_h = (const float*)d_in[15];
    const float* gamma_e = (const float*)d_in[16]; const float* beta_e = (const float*)d_in[17];

    float* ws    = (float*)d_ws;
    float* Uh    = ws;              // 1024*128
    float* Vh    = ws + 131072;
    float* Ahw   = ws + 262144;
    float* Bhw   = ws + 393216;
    float* aggS  = ws + 524288;
    float* aggA  = ws + 655360;
    float* h_new = ws + 786432;
    float* WCt   = ws + 917504;     // 128*128
    float* sums  = ws + 933888;     // 512: e_sum, e_ssq, h_sum, h_ssq
    float* outs  = ws + 934400;     // 512: e_scale, e_shift, h_scale, h_shift

    float* hout = (float*)d_out;
    float* eout = (float*)d_out + NROWS*HH;     // e_new then e_out, in place

    hipMemsetAsync(sums, 0, 512*sizeof(float), stream);
    k_linear4 <<<256,   256, 0, stream>>>(h, WU,bU, WV,bV, WA_,bA, WB_,bB, Uh);
    k_transpose<<<16,   256, 0, stream>>>(WC_, WCt);
    k_edge    <<<1024,  256, 0, stream>>>(e, A, S, WCt, bC, Ahw, Bhw, Vh,
                                          eout, aggS, aggA, sums);
    k_hnew    <<<128,   256, 0, stream>>>(Uh, aggS, aggA, h_new, sums);
    k_stats   <<<1,     128, 0, stream>>>(sums, outs, gamma_e, beta_e, gamma_h, beta_h);
    k_hout    <<<128,   256, 0, stream>>>(h, h_new, outs, hout);
    k_eout    <<<32768, 256, 0, stream>>>(e, outs, eout);
}

// Round 2
// 546.930 us; speedup vs baseline: 1.1212x; 1.1212x over previous
//
#include <hip/hip_runtime.h>

#define BB 4
#define VV 256
#define HH 128
#define NROWS (BB*VV)            // 1024
#define NE_CNT (BB*VV*VV)        // 262144
#define EPSV 1e-5f

typedef float4 f4;

__device__ __forceinline__ float sigm(float x) {
    return 1.f / (1.f + __expf(-x));
}

// ---------------------------------------------------------------------------
// K1: Uh/Vh/Ah/Bh = h @ W{U,V,A,B}^T + b   (1024 x 128, K=128)
// ---------------------------------------------------------------------------
__global__ __launch_bounds__(256) void k_linear4(
    const float* __restrict__ h,
    const float* __restrict__ W0, const float* __restrict__ b0,
    const float* __restrict__ W1, const float* __restrict__ b1,
    const float* __restrict__ W2, const float* __restrict__ b2,
    const float* __restrict__ W3, const float* __restrict__ b3,
    float* __restrict__ out)
{
    __shared__ float hs[4*HH];
    const int tid = threadIdx.x;
    const int r0  = blockIdx.x * 4;
    if (tid < 128) {
        int r = tid >> 5, kq = (tid & 31) << 2;
        *(f4*)&hs[r*HH + kq] = *(const f4*)&h[(r0 + r)*HH + kq];
    }
    __syncthreads();
    const int n  = tid & 127;
    const int s0 = tid >> 7;                       // 0 or 1
    const float* Ws[4] = {W0, W1, W2, W3};
    const float* bs[4] = {b0, b1, b2, b3};
    for (int ss = 0; ss < 2; ++ss) {
        const int sel = s0 + ss*2;
        const float* wrow = Ws[sel] + n*HH;
        float a0=0.f, a1=0.f, a2=0.f, a3=0.f;
        for (int kq = 0; kq < 32; ++kq) {
            f4 w = *(const f4*)&wrow[kq<<2];
            float wq[4] = {w.x, w.y, w.z, w.w};
            #pragma unroll
            for (int q = 0; q < 4; ++q) {
                int k = (kq<<2) + q;
                float wv = wq[q];
                a0 += hs[0*HH + k] * wv;
                a1 += hs[1*HH + k] * wv;
                a2 += hs[2*HH + k] * wv;
                a3 += hs[3*HH + k] * wv;
            }
        }
        float bias = bs[sel][n];
        float* o = out + sel*(NROWS*HH);
        o[(r0+0)*HH + n] = a0 + bias;
        o[(r0+1)*HH + n] = a1 + bias;
        o[(r0+2)*HH + n] = a2 + bias;
        o[(r0+3)*HH + n] = a3 + bias;
    }
}

// ---------------------------------------------------------------------------
// K1b: WCt[k][n] = WC[n][k]  (128x128, LDS-tiled transpose)
// ---------------------------------------------------------------------------
__global__ __launch_bounds__(256) void k_transpose(
    const float* __restrict__ in, float* __restrict__ out)
{
    __shared__ float t[32][33];
    int ti = blockIdx.x >> 2, tj = blockIdx.x & 3;
    int tx = threadIdx.x & 31, ty = threadIdx.x >> 5;   // ty 0..7
    for (int yy = ty; yy < 32; yy += 8)
        t[yy][tx] = in[(ti*32 + yy)*HH + tj*32 + tx];
    __syncthreads();
    for (int yy = ty; yy < 32; yy += 8)
        out[(tj*32 + yy)*HH + ti*32 + tx] = t[tx][yy];
}

// ---------------------------------------------------------------------------
// K2 v2: per (b,i): Ce GEMM (256j x 128n, K=128) fused with e_new epilogue.
// Thread tile 8j x 16n (acc 128 VGPR). tn=tid&7 (n = tn*4+q*32+qq),
// tjg=tid>>3 (j = tjg + 32*jj). Per 4k-group/wave: 24 ds_read_b128 (288 cyc)
// vs 1024 VALU cyc -> ~89% VALU ceiling. es stride 36 (144B, 16B-aligned),
// wc stride 132: both operand reads conflict-free per-instruction (8 disjoint
// 4-bank groups across lanes, broadcast over the other lane dim).
// ---------------------------------------------------------------------------
__global__ __launch_bounds__(256, 2) void k_edge(
    const float* __restrict__ e, const int* __restrict__ A, const int* __restrict__ S,
    const float* __restrict__ WCt, const float* __restrict__ bC,
    const float* __restrict__ Ahw, const float* __restrict__ Bhw,
    const float* __restrict__ Vhw,
    float* __restrict__ eout, float* __restrict__ aggS, float* __restrict__ aggA,
    float* __restrict__ sums)
{
    __shared__ float es[256*36];         // 36 KB, row stride 36 floats
    __shared__ float wc[32*132];         // 16.5 KB, row stride 132 floats
    __shared__ float s_aggS[HH], s_aggA[HH], s_sum[HH], s_ssq[HH];

    const int t  = threadIdx.x;
    const int bi = blockIdx.x;           // b*V + i
    const int b  = bi >> 8;
    if (t < HH) { s_aggS[t]=0.f; s_aggA[t]=0.f; s_sum[t]=0.f; s_ssq[t]=0.f; }

    const int tn  = t & 7;               // n0 = tn*4 (+q*32)
    const int tjg = t >> 3;              // j = tjg + 32*jj

    float acc[8][16];
    #pragma unroll
    for (int jj = 0; jj < 8; ++jj)
        #pragma unroll
        for (int q = 0; q < 16; ++q) acc[jj][q] = 0.f;

    const f4* e4   = (const f4*)e;
    const f4* wct4 = (const f4*)WCt;

    for (int kc = 0; kc < 4; ++kc) {     // K chunks of 32
        __syncthreads();
        #pragma unroll
        for (int m = 0; m < 8; ++m) {    // stage es: 256j x 32k
            int idx = m*256 + t;
            int j = idx >> 3, kq = idx & 7;
            *(f4*)&es[j*36 + kq*4] = e4[(bi*VV + j)*32 + kc*8 + kq];
        }
        #pragma unroll
        for (int m = 0; m < 4; ++m) {    // stage wc: 32k x 128n
            int idx = m*256 + t;
            int k = idx >> 5, n4 = idx & 31;
            *(f4*)&wc[k*132 + n4*4] = wct4[(kc*32 + k)*32 + n4];
        }
        __syncthreads();
        #pragma unroll
        for (int kq = 0; kq < 8; ++kq) { // 4-k groups
            f4 aj[8];
            #pragma unroll
            for (int jj = 0; jj < 8; ++jj)
                aj[jj] = *(const f4*)&es[(tjg + jj*32)*36 + kq*4];
            #pragma unroll
            for (int kk = 0; kk < 4; ++kk) {
                f4 wq[4];
                #pragma unroll
                for (int q = 0; q < 4; ++q)
                    wq[q] = *(const f4*)&wc[(kq*4 + kk)*132 + tn*4 + q*32];
                #pragma unroll
                for (int jj = 0; jj < 8; ++jj) {
                    float a = (kk==0) ? aj[jj].x : (kk==1) ? aj[jj].y
                            : (kk==2) ? aj[jj].z : aj[jj].w;
                    #pragma unroll
                    for (int q = 0; q < 4; ++q) {
                        acc[jj][q*4+0] += a*wq[q].x;
                        acc[jj][q*4+1] += a*wq[q].y;
                        acc[jj][q*4+2] += a*wq[q].z;
                        acc[jj][q*4+3] += a*wq[q].w;
                    }
                }
            }
        }
    }

    // ---- epilogue: e_new = acc + bC + Bh[i] + Ah[j]; store; stats; aggs ----
    float bcv[16], bhv[16];
    #pragma unroll
    for (int q = 0; q < 4; ++q) {
        f4 bc4 = *(const f4*)&bC[tn*4 + q*32];
        f4 bh4 = *(const f4*)&Bhw[bi*HH + tn*4 + q*32];
        bcv[q*4+0]=bc4.x; bcv[q*4+1]=bc4.y; bcv[q*4+2]=bc4.z; bcv[q*4+3]=bc4.w;
        bhv[q*4+0]=bh4.x; bhv[q*4+1]=bh4.y; bhv[q*4+2]=bh4.z; bhv[q*4+3]=bh4.w;
    }
    float sm[16], sq[16], aS[16], aA[16];
    #pragma unroll
    for (int q = 0; q < 16; ++q) { sm[q]=0.f; sq[q]=0.f; aS[q]=0.f; aA[q]=0.f; }

    const int* Sp = S + bi*VV;
    const int* Ap = A + bi*VV;
    #pragma unroll
    for (int jj = 0; jj < 8; ++jj) {
        const int j = tjg + jj*32;
        const float* ahp = &Ahw[(b*VV + j)*HH];
        const float* vhp = &Vhw[(b*VV + j)*HH];
        const int Sij = Sp[j], Aij = Ap[j];
        #pragma unroll
        for (int q = 0; q < 4; ++q) {
            f4 ah = *(const f4*)&ahp[tn*4 + q*32];
            f4 vh = *(const f4*)&vhp[tn*4 + q*32];
            f4 env;
            env.x = acc[jj][q*4+0] + bcv[q*4+0] + bhv[q*4+0] + ah.x;
            env.y = acc[jj][q*4+1] + bcv[q*4+1] + bhv[q*4+1] + ah.y;
            env.z = acc[jj][q*4+2] + bcv[q*4+2] + bhv[q*4+2] + ah.z;
            env.w = acc[jj][q*4+3] + bcv[q*4+3] + bhv[q*4+3] + ah.w;
            *(f4*)&eout[((size_t)(bi*VV) + j)*HH + tn*4 + q*32] = env;
            float vv[4] = {vh.x, vh.y, vh.z, vh.w};
            float ev[4] = {env.x, env.y, env.z, env.w};
            #pragma unroll
            for (int qq = 0; qq < 4; ++qq) {
                float v = ev[qq];
                sm[q*4+qq] += v;
                sq[q*4+qq] += v*v;
                if (!Aij) aA[q*4+qq] += vv[qq];
                if (!Sij) aS[q*4+qq] += vv[qq] * sigm(v);
            }
        }
    }
    #pragma unroll
    for (int q = 0; q < 4; ++q)
        #pragma unroll
        for (int qq = 0; qq < 4; ++qq) {
            int n = tn*4 + q*32 + qq;
            atomicAdd(&s_sum[n],  sm[q*4+qq]);
            atomicAdd(&s_ssq[n],  sq[q*4+qq]);
            atomicAdd(&s_aggS[n], aS[q*4+qq]);
            atomicAdd(&s_aggA[n], aA[q*4+qq]);
        }
    __syncthreads();
    if (t < HH) {
        aggS[bi*HH + t] = s_aggS[t];
        aggA[bi*HH + t] = s_aggA[t];
        atomicAdd(&sums[t],      s_sum[t]);   // e channel sum
        atomicAdd(&sums[HH + t], s_ssq[t]);   // e channel sumsq
    }
}

// ---------------------------------------------------------------------------
// K3a: h_new = Uh + aggS + aggA ; accumulate h channel sums
// ---------------------------------------------------------------------------
__global__ __launch_bounds__(256) void k_hnew(
    const float* __restrict__ Uh, const float* __restrict__ aggS,
    const float* __restrict__ aggA, float* __restrict__ h_new,
    float* __restrict__ sums)
{
    __shared__ float ssm[HH], ssq[HH];
    const int tid = threadIdx.x;
    if (tid < 128) { ssm[tid]=0.f; ssq[tid]=0.f; }
    __syncthreads();
    int gid = blockIdx.x*256 + tid;
    f4 u = *(const f4*)&Uh[gid*4];
    f4 s = *(const f4*)&aggS[gid*4];
    f4 a = *(const f4*)&aggA[gid*4];
    float v0=u.x+s.x+a.x, v1=u.y+s.y+a.y, v2=u.z+s.z+a.z, v3=u.w+s.w+a.w;
    *(f4*)&h_new[gid*4] = make_float4(v0,v1,v2,v3);
    int n0 = (gid*4) & 127;
    atomicAdd(&ssm[n0+0], v0); atomicAdd(&ssq[n0+0], v0*v0);
    atomicAdd(&ssm[n0+1], v1); atomicAdd(&ssq[n0+1], v1*v1);
    atomicAdd(&ssm[n0+2], v2); atomicAdd(&ssq[n0+2], v2*v2);
    atomicAdd(&ssm[n0+3], v3); atomicAdd(&ssq[n0+3], v3*v3);
    __syncthreads();
    if (tid < 128) {
        atomicAdd(&sums[256 + tid], ssm[tid]);
        atomicAdd(&sums[384 + tid], ssq[tid]);
    }
}

// ---------------------------------------------------------------------------
// K3b: finalize batchnorm params -> scale/shift per channel
// ---------------------------------------------------------------------------
__global__ void k_stats(const float* __restrict__ sums, float* __restrict__ outs,
                        const float* __restrict__ gamma_e, const float* __restrict__ beta_e,
                        const float* __restrict__ gamma_h, const float* __restrict__ beta_h)
{
    int n = threadIdx.x;   // 128
    float em  = sums[n] * (1.f/(float)NE_CNT);
    float ev  = sums[128+n] * (1.f/(float)NE_CNT) - em*em;
    float esc = rsqrtf(ev + EPSV) * gamma_e[n];
    outs[n]       = esc;
    outs[128 + n] = beta_e[n] - em*esc;
    float hm  = sums[256+n] * (1.f/1024.f);
    float hv  = sums[384+n] * (1.f/1024.f) - hm*hm;
    float hsc = rsqrtf(hv + EPSV) * gamma_h[n];
    outs[256 + n] = hsc;
    outs[384 + n] = beta_h[n] - hm*hsc;
}

// ---------------------------------------------------------------------------
// K4h: h_out = h_in + relu(bn(h_new))
// ---------------------------------------------------------------------------
__global__ __launch_bounds__(256) void k_hout(
    const float* __restrict__ h_in, const float* __restrict__ h_new,
    const float* __restrict__ outs, float* __restrict__ hout)
{
    int gid = blockIdx.x*256 + threadIdx.x;
    int n0 = (gid*4) & 127;
    f4 x  = *(const f4*)&h_new[gid*4];
    f4 hi = *(const f4*)&h_in[gid*4];
    f4 sc = *(const f4*)&outs[256 + n0];
    f4 sh = *(const f4*)&outs[384 + n0];
    f4 y;
    y.x = fmaxf(x.x*sc.x + sh.x, 0.f) + hi.x;
    y.y = fmaxf(x.y*sc.y + sh.y, 0.f) + hi.y;
    y.z = fmaxf(x.z*sc.z + sh.z, 0.f) + hi.z;
    y.w = fmaxf(x.w*sc.w + sh.w, 0.f) + hi.w;
    *(f4*)&hout[gid*4] = y;
}

// ---------------------------------------------------------------------------
// K4e: e_out = e_in + relu(bn(e_new))   (e_new lives in-place in d_out)
// ---------------------------------------------------------------------------
__global__ __launch_bounds__(256) void k_eout(
    const float* __restrict__ e_in, const float* __restrict__ outs,
    float* __restrict__ eio)
{
    size_t gid = (size_t)blockIdx.x*256 + threadIdx.x;
    int n0 = ((int)(gid & 31)) << 2;
    f4 x  = *(const f4*)&eio[gid*4];
    f4 ei = *(const f4*)&e_in[gid*4];
    f4 sc = *(const f4*)&outs[n0];
    f4 sh = *(const f4*)&outs[128 + n0];
    f4 y;
    y.x = fmaxf(x.x*sc.x + sh.x, 0.f) + ei.x;
    y.y = fmaxf(x.y*sc.y + sh.y, 0.f) + ei.y;
    y.z = fmaxf(x.z*sc.z + sh.z, 0.f) + ei.z;
    y.w = fmaxf(x.w*sc.w + sh.w, 0.f) + ei.w;
    *(f4*)&eio[gid*4] = y;
}

// ---------------------------------------------------------------------------
extern "C" void kernel_launch(void* const* d_in, const int* in_sizes, int n_in,
                              void* d_out, int out_size, void* d_ws, size_t ws_size,
                              hipStream_t stream)
{
    (void)in_sizes; (void)n_in; (void)out_size; (void)ws_size;
    const float* h   = (const float*)d_in[0];
    const float* e   = (const float*)d_in[1];
    const int*   A   = (const int*)d_in[2];
    const int*   S   = (const int*)d_in[3];
    const float* WU  = (const float*)d_in[4];   const float* bU = (const float*)d_in[5];
    const float* WV  = (const float*)d_in[6];   const float* bV = (const float*)d_in[7];
    const float* WA_ = (const float*)d_in[8];   const float* bA = (const float*)d_in[9];
    const float* WB_ = (const float*)d_in[10];  const float* bB = (const float*)d_in[11];
    const float* WC_ = (const float*)d_in[12];  const float* bC = (const float*)d_in[13];
    const float* gamma_h = (const float*)d_in[14]; const float* beta_h = (const float*)d_in[15];
    const float* gamma_e = (const float*)d_in[16]; const float* beta_e = (const float*)d_in[17];

    float* ws    = (float*)d_ws;
    float* Uh    = ws;              // 1024*128
    float* Vh    = ws + 131072;
    float* Ahw   = ws + 262144;
    float* Bhw   = ws + 393216;
    float* aggS  = ws + 524288;
    float* aggA  = ws + 655360;
    float* h_new = ws + 786432;
    float* WCt   = ws + 917504;     // 128*128
    float* sums  = ws + 933888;     // 512: e_sum, e_ssq, h_sum, h_ssq
    float* outs  = ws + 934400;     // 512: e_scale, e_shift, h_scale, h_shift

    float* hout = (float*)d_out;
    float* eout = (float*)d_out + NROWS*HH;     // e_new then e_out, in place

    hipMemsetAsync(sums, 0, 512*sizeof(float), stream);
    k_linear4 <<<256,   256, 0, stream>>>(h, WU,bU, WV,bV, WA_,bA, WB_,bB, Uh);
    k_transpose<<<16,   256, 0, stream>>>(WC_, WCt);
    k_edge    <<<1024,  256, 0, stream>>>(e, A, S, WCt, bC, Ahw, Bhw, Vh,
                                          eout, aggS, aggA, sums);
    k_hnew    <<<128,   256, 0, stream>>>(Uh, aggS, aggA, h_new, sums);
    k_stats   <<<1,     128, 0, stream>>>(sums, outs, gamma_e, beta_e, gamma_h, beta_h);
    k_hout    <<<128,   256, 0, stream>>>(h, h_new, outs, hout);
    k_eout    <<<32768, 256, 0, stream>>>(e, outs, eout);
}